// Round 2
// baseline (26.998 us; speedup 1.0000x reference)
//
#include <hip/hip_runtime.h>
#include <math.h>

#define PI_F 3.14159274101257324f   // (float)M_PI
#ifndef M_PI
#define M_PI 3.14159265358979323846
#endif

// x: (16,1,512,512) f32 ; out: (16,10,64,64) f32
// thread t -> (n, ch, cw, r): r = t & 7 (pixel row within 8x8 cell)
__global__ void __launch_bounds__(256) hog_kernel(const float* __restrict__ x,
                                                  float* __restrict__ out) {
    int t = blockIdx.x * blockDim.x + threadIdx.x;
    int r    = t & 7;
    int cell = t >> 3;           // 0 .. 65535
    int cw   = cell & 63;
    int ch   = (cell >> 6) & 63;
    int n    = cell >> 12;

    const float* img = x + (size_t)n * (512 * 512);
    int row  = ch * 8 + r;       // pixel row this thread handles
    int col0 = cw * 8;           // first pixel column of the cell

    // Load 3 rows x 10 cols with zero padding (conv halo)
    float xr[3][10];
#pragma unroll
    for (int dr = 0; dr < 3; ++dr) {
        int rr = row + dr - 1;
        bool rok = (rr >= 0) && (rr < 512);
        const float* rp = img + (size_t)(rok ? rr : 0) * 512;
#pragma unroll
        for (int c = 0; c < 10; ++c) {
            int cc = col0 + c - 1;
            bool ok = rok && (cc >= 0) && (cc < 512);
            xr[dr][c] = ok ? rp[cc] : 0.0f;
        }
    }

    float bins[10];
#pragma unroll
    for (int b = 0; b < 10; ++b) bins[b] = 0.0f;

#pragma unroll
    for (int c = 0; c < 8; ++c) {
        float a0 = xr[0][c], a1 = xr[0][c + 1], a2 = xr[0][c + 2];
        float b0 = xr[1][c],                    b2 = xr[1][c + 2];
        float c0 = xr[2][c], c1 = xr[2][c + 1], c2 = xr[2][c + 2];

        // Row-major tap-order association (matches a straightforward conv loop).
        // gx taps: [[1,0,-1],[2,0,-2],[1,0,-1]], gy taps: [[1,2,1],[0,0,0],[-1,-2,-1]]
        float gx = ((((a0 - a2) + 2.0f * b0) - 2.0f * b2) + c0) - c2;
        float gy = ((((a0 + 2.0f * a1) + a2) - c0) - 2.0f * c1) - c2;

        float mag = sqrtf(gx * gx + gy * gy);
        float p   = atan2f(gx, gy) / PI_F * 10.0f;   // ref: atan2(gx, gy)/pi*10

        float d = fabsf(p - rintf(p));
        int fl, ce;
        if (d * fminf(mag, 1.0f) < 3e-4f) {
            // Boundary-accurate path: exact conv in double + double atan2.
            double gxd = ((((((double)a0 - (double)a2) + 2.0 * (double)b0)
                            - 2.0 * (double)b2) + (double)c0) - (double)c2);
            double gyd = ((((((double)a0 + 2.0 * (double)a1) + (double)a2)
                            - (double)c0) - 2.0 * (double)c1) - (double)c2);
            if (gxd == 0.0) {                 // phase = 0 or +-pi -> p = 0 / +-10 -> bin 0
                fl = 0; ce = 0;
            } else if (gyd == 0.0) {          // phase = +-pi/2 -> p = +-5 exactly -> bin 5
                fl = 5; ce = 5;
            } else {
                double pt = atan2(gxd, gyd) * (10.0 / M_PI);
                int fli = (int)floor(pt);
                int cei = (int)ceil(pt);
                fl = ((fli % 10) + 10) % 10;
                ce = ((cei % 10) + 10) % 10;
            }
        } else {
            int fli = (int)floorf(p);
            int cei = (int)ceilf(p);
            fl = ((fli % 10) + 10) % 10;
            ce = ((cei % 10) + 10) % 10;
        }

        float om = 1.0f - mag;
#pragma unroll
        for (int b = 0; b < 10; ++b) {
            bins[b] += (b == fl ? mag : 0.0f) + (b == ce ? om : 0.0f);
        }
    }

    // Reduce the 8 row-threads of each cell (lanes r=0..7 contiguous)
#pragma unroll
    for (int b = 0; b < 10; ++b) {
        float v = bins[b];
        v += __shfl_xor(v, 1);
        v += __shfl_xor(v, 2);
        v += __shfl_xor(v, 4);
        bins[b] = v;
    }

    if (r == 0) {
        float* op = out + (((size_t)n * 10) * 64 + ch) * 64 + cw;
#pragma unroll
        for (int b = 0; b < 10; ++b) {
            op[(size_t)b * 4096] = bins[b] * (1.0f / 64.0f);
        }
    }
}

extern "C" void kernel_launch(void* const* d_in, const int* in_sizes, int n_in,
                              void* d_out, int out_size, void* d_ws, size_t ws_size,
                              hipStream_t stream) {
    const float* x = (const float*)d_in[0];
    float* out = (float*)d_out;
    const int total = 16 * 64 * 64 * 8;  // 524288 threads
    hog_kernel<<<total / 256, 256, 0, stream>>>(x, out);
}